// Round 5
// baseline (159.661 us; speedup 1.0000x reference)
//
#include <hip/hip_runtime.h>

// (B,N,H,NB,NCT) = (8,4096,1024,128,33), H/2 = 512
#define NTOK 4096
#define HDIM 1024
#define HHALF 512
#define NBLK 128
#define CAP 256
#define XELEMS 33554432ull   // 8*4096*1024

typedef __attribute__((ext_vector_type(8))) short short8;
typedef __attribute__((ext_vector_type(4))) float f32x4;
typedef short bf16s;

__device__ __forceinline__ short f2bf(float f) {
    unsigned u = __builtin_bit_cast(unsigned, f);
    u = (u + 0x7fffu + ((u >> 16) & 1u)) >> 16;   // RNE
    return (short)u;
}
__device__ __forceinline__ void gload_lds16(const void* g, void* l) {
    __builtin_amdgcn_global_load_lds(
        (const __attribute__((address_space(1))) unsigned int*)g,
        (__attribute__((address_space(3))) unsigned int*)l, 16, 0, 0);
}
__device__ __forceinline__ float fast_tanh(float v) {
    float e = __expf(2.0f * v);
    return 1.0f - 2.0f / (e + 1.0f);
}

// ---------------------------------------------------------------------------
// x (f32) -> xb (bf16), grid-stride, vectorized. Memory-bound.
// ---------------------------------------------------------------------------
__global__ void k_xcvt(const float* __restrict__ in, bf16s* __restrict__ out) {
    for (size_t i = ((size_t)blockIdx.x * 256 + threadIdx.x) * 8; i < XELEMS;
         i += (size_t)gridDim.x * 256 * 8) {
        float4 a = *reinterpret_cast<const float4*>(&in[i]);
        float4 b = *reinterpret_cast<const float4*>(&in[i + 4]);
        short h[8] = {f2bf(a.x), f2bf(a.y), f2bf(a.z), f2bf(a.w),
                      f2bf(b.x), f2bf(b.y), f2bf(b.z), f2bf(b.w)};
        *reinterpret_cast<int4*>(&out[i]) = *reinterpret_cast<const int4*>(h);
    }
}

// ---------------------------------------------------------------------------
// Tiled transpose+convert for both weights in one launch.
// ---------------------------------------------------------------------------
__global__ void k_tcvt2(const float* __restrict__ W1, const float* __restrict__ Wp,
                        bf16s* __restrict__ w1t, bf16s* __restrict__ wpt) {
    __shared__ float tile[64][65];
    const int by = blockIdx.y;
    const float* in = (by < 8) ? W1 : Wp;
    bf16s* out = (by < 8) ? w1t : wpt;
    const int Nc = (by < 8) ? HHALF : HDIM;
    const int n0 = ((by < 8) ? by : (by - 8)) * 64;
    const int k0 = blockIdx.x * 64;
    const int tx = threadIdx.x & 63, ty = threadIdx.x >> 6;
    #pragma unroll
    for (int i = 0; i < 16; ++i) {
        int r = ty + i * 4;
        tile[r][tx] = in[(size_t)(k0 + r) * Nc + n0 + tx];
    }
    __syncthreads();
    #pragma unroll
    for (int i = 0; i < 16; ++i) {
        int r = ty + i * 4;
        out[(size_t)(n0 + r) * 1024 + k0 + tx] = f2bf(tile[tx][r]);
    }
}

// ---------------------------------------------------------------------------
// Gate GEMM (m97 structure, pure-gll both operands, bf16 in):
// partial[ct][row] = sum over col-tile ct's 128 cols of tanh(h+b1)*W2.
// 128x128 tile, BK=32, 4 waves (2x2), acc[4][4], single-buffer 2-barrier.
// ---------------------------------------------------------------------------
__global__ __launch_bounds__(256, 4) void k_gemm_g(
    const bf16s* __restrict__ xb, const bf16s* __restrict__ w1t,
    const float* __restrict__ b1, const float* __restrict__ w2,
    float* __restrict__ partial)
{
    __shared__ alignas(16) bf16s As[128 * 32];   // linear gll dest, swizzled src
    __shared__ alignas(16) bf16s Bs[128 * 32];
    __shared__ float gp[2][128];

    const int tid = threadIdx.x;
    const int lane = tid & 63;
    const int wv = tid >> 6;
    const int wr = wv >> 1, wc = wv & 1;
    const int phys = blockIdx.x;
    const int logical = (phys & 7) * 128 + (phys >> 3);   // 1024 = 8*128 bijective
    const int row0 = (logical >> 2) * 128;
    const int col0 = (logical & 3) * 128;
    const int c0 = lane & 15, khalf = lane >> 4;

    // staging geometry (identical verified pattern for A and B)
    const int srow = wv * 32 + (lane >> 2);   // + q*16
    const int sj = lane & 3;

    f32x4 acc[4][4] = {};

    for (int t = 0; t < 32; ++t) {
        const int kt = t * 32;
        __syncthreads();                       // all waves done reading LDS
        #pragma unroll
        for (int q = 0; q < 2; ++q) {
            int r = srow + q * 16;
            int j = sj ^ ((r >> 1) & 3);
            gload_lds16(&xb[(size_t)(row0 + r) * HDIM + kt + j * 8],
                        &As[(wv * 32 + q * 16) * 32 + lane * 8]);
            gload_lds16(&w1t[(size_t)(col0 + r) * HDIM + kt + j * 8],
                        &Bs[(wv * 32 + q * 16) * 32 + lane * 8]);
        }
        __syncthreads();                       // tiles ready
        const int kk = khalf;
        short8 av[4];
        #pragma unroll
        for (int mf = 0; mf < 4; ++mf) {
            int ra = wr * 64 + mf * 16 + c0;
            av[mf] = *reinterpret_cast<const short8*>(
                &As[ra * 32 + ((kk ^ ((ra >> 1) & 3)) * 8)]);
        }
        #pragma unroll
        for (int nf = 0; nf < 4; ++nf) {
            int rb = wc * 64 + nf * 16 + c0;
            short8 bv = *reinterpret_cast<const short8*>(
                &Bs[rb * 32 + ((kk ^ ((rb >> 1) & 3)) * 8)]);
            #pragma unroll
            for (int mf = 0; mf < 4; ++mf)
                acc[mf][nf] = __builtin_amdgcn_mfma_f32_16x16x32_bf16(av[mf], bv, acc[mf][nf], 0, 0, 0);
        }
    }

    // epilogue: per-row partial dot of tanh(h)*W2 over this wave's 64 cols
    float b1v[4], w2v[4];
    #pragma unroll
    for (int nf = 0; nf < 4; ++nf) {
        int gc = col0 + wc * 64 + nf * 16 + c0;
        b1v[nf] = b1[gc];
        w2v[nf] = w2[gc];
    }
    #pragma unroll
    for (int mf = 0; mf < 4; ++mf) {
        #pragma unroll
        for (int reg = 0; reg < 4; ++reg) {
            float s = 0.f;
            #pragma unroll
            for (int nf = 0; nf < 4; ++nf)
                s += fast_tanh(acc[mf][nf][reg] + b1v[nf]) * w2v[nf];
            s += __shfl_xor(s, 1); s += __shfl_xor(s, 2);
            s += __shfl_xor(s, 4); s += __shfl_xor(s, 8);
            if (c0 == 0) gp[wc][wr * 64 + mf * 16 + khalf * 4 + reg] = s;
        }
    }
    __syncthreads();
    if (tid < 128)
        partial[(size_t)(logical & 3) * 32768 + row0 + tid] = gp[0][tid] + gp[1][tid];
}

// ---------------------------------------------------------------------------
// FALLBACK gate GEMM (R4 path, f32 x) — used only if ws can't hold xb.
// ---------------------------------------------------------------------------
__global__ __launch_bounds__(256, 3) void k_gemm_h(
    const float* __restrict__ x, const bf16s* __restrict__ w1t,
    const float* __restrict__ b1, const float* __restrict__ w2,
    float* __restrict__ partial)
{
    __shared__ alignas(16) bf16s As[128 * 36];
    __shared__ alignas(16) bf16s Bs[128 * 32];
    __shared__ float gp[2][128];

    const int tid = threadIdx.x;
    const int lane = tid & 63;
    const int wv = tid >> 6;
    const int wr = wv >> 1, wc = wv & 1;
    const int phys = blockIdx.x;
    const int logical = (phys & 7) * 128 + (phys >> 3);
    const int row0 = (logical >> 2) * 128;
    const int col0 = (logical & 3) * 128;
    const int c0 = lane & 15, khalf = lane >> 4;

    const int ar = tid >> 1, ah = tid & 1;
    const float* xsrc = &x[(size_t)(row0 + ar) * HDIM + ah * 16];
    const int brow = wv * 32 + (lane >> 2);
    const int bj = lane & 3;

    f32x4 acc[4][4] = {};
    float4 pa0 = *reinterpret_cast<const float4*>(xsrc);
    float4 pa1 = *reinterpret_cast<const float4*>(xsrc + 4);
    float4 pa2 = *reinterpret_cast<const float4*>(xsrc + 8);
    float4 pa3 = *reinterpret_cast<const float4*>(xsrc + 12);

    for (int t = 0; t < 32; ++t) {
        const int kt = t * 32;
        __syncthreads();
        {
            short h[16] = {f2bf(pa0.x), f2bf(pa0.y), f2bf(pa0.z), f2bf(pa0.w),
                           f2bf(pa1.x), f2bf(pa1.y), f2bf(pa1.z), f2bf(pa1.w),
                           f2bf(pa2.x), f2bf(pa2.y), f2bf(pa2.z), f2bf(pa2.w),
                           f2bf(pa3.x), f2bf(pa3.y), f2bf(pa3.z), f2bf(pa3.w)};
            *reinterpret_cast<int4*>(&As[ar * 36 + ah * 16]) =
                *reinterpret_cast<const int4*>(&h[0]);
            *reinterpret_cast<int4*>(&As[ar * 36 + ah * 16 + 8]) =
                *reinterpret_cast<const int4*>(&h[8]);
        }
        #pragma unroll
        for (int q = 0; q < 2; ++q) {
            int r = brow + q * 16;
            int j = bj ^ ((r >> 1) & 3);
            gload_lds16(&w1t[(size_t)(col0 + r) * HDIM + kt + j * 8],
                        &Bs[(wv * 32 + q * 16) * 32 + lane * 8]);
        }
        __syncthreads();
        if (t < 31) {
            pa0 = *reinterpret_cast<const float4*>(xsrc + kt + 32);
            pa1 = *reinterpret_cast<const float4*>(xsrc + kt + 36);
            pa2 = *reinterpret_cast<const float4*>(xsrc + kt + 40);
            pa3 = *reinterpret_cast<const float4*>(xsrc + kt + 44);
        }
        const int kk = khalf * 8;
        short8 av[4];
        #pragma unroll
        for (int mf = 0; mf < 4; ++mf)
            av[mf] = *reinterpret_cast<const short8*>(
                &As[(wr * 64 + mf * 16 + c0) * 36 + kk]);
        #pragma unroll
        for (int nf = 0; nf < 4; ++nf) {
            int rb = wc * 64 + nf * 16 + c0;
            short8 bv = *reinterpret_cast<const short8*>(
                &Bs[rb * 32 + ((khalf ^ ((rb >> 1) & 3)) * 8)]);
            #pragma unroll
            for (int mf = 0; mf < 4; ++mf)
                acc[mf][nf] = __builtin_amdgcn_mfma_f32_16x16x32_bf16(av[mf], bv, acc[mf][nf], 0, 0, 0);
        }
    }
    float b1v[4], w2v[4];
    #pragma unroll
    for (int nf = 0; nf < 4; ++nf) {
        int gc = col0 + wc * 64 + nf * 16 + c0;
        b1v[nf] = b1[gc];
        w2v[nf] = w2[gc];
    }
    #pragma unroll
    for (int mf = 0; mf < 4; ++mf) {
        #pragma unroll
        for (int reg = 0; reg < 4; ++reg) {
            float s = 0.f;
            #pragma unroll
            for (int nf = 0; nf < 4; ++nf)
                s += fast_tanh(acc[mf][nf][reg] + b1v[nf]) * w2v[nf];
            s += __shfl_xor(s, 1); s += __shfl_xor(s, 2);
            s += __shfl_xor(s, 4); s += __shfl_xor(s, 8);
            if (c0 == 0) gp[wc][wr * 64 + mf * 16 + khalf * 4 + reg] = s;
        }
    }
    __syncthreads();
    if (tid < 128)
        partial[(size_t)(logical & 3) * 32768 + row0 + tid] = gp[0][tid] + gp[1][tid];
}

// ---------------------------------------------------------------------------
__global__ void k_gate_sum(const float* __restrict__ partial, const float* __restrict__ b2,
                           float* __restrict__ gate) {
    int i = (blockIdx.x * 256 + threadIdx.x) * 4;
    float4 p0 = *reinterpret_cast<const float4*>(&partial[i]);
    float4 p1 = *reinterpret_cast<const float4*>(&partial[32768 + i]);
    float4 p2 = *reinterpret_cast<const float4*>(&partial[65536 + i]);
    float4 p3 = *reinterpret_cast<const float4*>(&partial[98304 + i]);
    float bb = b2[0];
    float4 o = {p0.x + p1.x + p2.x + p3.x + bb, p0.y + p1.y + p2.y + p3.y + bb,
                p0.z + p1.z + p2.z + p3.z + bb, p0.w + p1.w + p2.w + p3.w + bb};
    *reinterpret_cast<float4*>(&gate[i]) = o;
}

// ---------------------------------------------------------------------------
// Single-pass per-(b,block): online-softmax stats + ordered member lists.
// ---------------------------------------------------------------------------
__global__ void k_blocks(const int* __restrict__ block_ids, const unsigned char* __restrict__ pad,
                         const float* __restrict__ gate, const int* __restrict__ ct,
                         const float* __restrict__ ct_emb,
                         int* __restrict__ counts, float* __restrict__ mblk,
                         float* __restrict__ wscale, int* __restrict__ lists,
                         float* __restrict__ out_hasb)
{
    const int blk = blockIdx.x;
    const int b = blk >> 7, k = blk & 127;
    const int lane = threadIdx.x;
    const int base = b * NTOK;
    const int lbase = blk * CAP;
    const unsigned long long ltmask = (1ull << lane) - 1ull;

    float m = -__builtin_inff();
    float s = 0.f;
    int pos = 0;
    for (int t0 = 0; t0 < NTOK; t0 += 64) {
        int t = t0 + lane;
        bool mt = (block_ids[base + t] == k) && (pad[base + t] == 0);
        float g = gate[base + t];
        unsigned long long mask = __ballot(mt);
        if (mt) {
            int my = pos + __popcll(mask & ltmask);
            if (my < CAP) lists[lbase + my] = t;
            float mn = fmaxf(m, g);
            s = s * __expf(m - mn) + __expf(g - mn);
            m = mn;
        }
        pos += __popcll(mask);
    }
    #pragma unroll
    for (int off = 1; off < 64; off <<= 1) {
        float om = __shfl_xor(m, off);
        float os = __shfl_xor(s, off);
        float mn = fmaxf(m, om);
        float sa = (m == -__builtin_inff()) ? 0.f : s * __expf(m - mn);
        float sb = (om == -__builtin_inff()) ? 0.f : os * __expf(om - mn);
        s = sa + sb;
        m = mn;
    }
    if (lane == 0) {
        counts[blk] = pos;
        mblk[blk] = (pos > 0) ? m : 0.f;
        float mod = 1.0f + 0.1f * ct_emb[ct[b] * NBLK + k];
        wscale[blk] = (pos > 0 && s > 0.f) ? (mod / fmaxf(s, 1e-30f)) : 0.f;
        out_hasb[blk] = (pos > 0) ? 1.f : 0.f;
    }
}

// ---------------------------------------------------------------------------
// Pooling from bf16 xb (or f32 x fallback).
// ---------------------------------------------------------------------------
__global__ void k_pool(const float* __restrict__ x, const bf16s* __restrict__ xb, int use_bf,
                       const float* __restrict__ gate,
                       const int* __restrict__ lists, const int* __restrict__ counts,
                       const float* __restrict__ mblk, const float* __restrict__ wscale,
                       bf16s* __restrict__ pooled)
{
    const int blk = blockIdx.x;
    const int b = blk >> 7;
    const int tid = threadIdx.x;
    const int base = b * NTOK;
    const int cnt = min(counts[blk], CAP);
    const int lbase = blk * CAP;
    const float m = mblk[blk], ws = wscale[blk];

    float4 acc = {0.f, 0.f, 0.f, 0.f};
    for (int i = 0; i < cnt; ++i) {
        int n = lists[lbase + i];
        float w = __expf(gate[base + n] - m);
        float4 xv;
        if (use_bf) {
            int2 rv = *reinterpret_cast<const int2*>(&xb[(size_t)(base + n) * HDIM + tid * 4]);
            short s4[4];
            *reinterpret_cast<int2*>(s4) = rv;
            unsigned u0 = ((unsigned)(unsigned short)s4[0]) << 16;
            unsigned u1 = ((unsigned)(unsigned short)s4[1]) << 16;
            unsigned u2 = ((unsigned)(unsigned short)s4[2]) << 16;
            unsigned u3 = ((unsigned)(unsigned short)s4[3]) << 16;
            xv.x = __builtin_bit_cast(float, u0); xv.y = __builtin_bit_cast(float, u1);
            xv.z = __builtin_bit_cast(float, u2); xv.w = __builtin_bit_cast(float, u3);
        } else {
            xv = *reinterpret_cast<const float4*>(&x[(size_t)(base + n) * HDIM + tid * 4]);
        }
        acc.x += w * xv.x; acc.y += w * xv.y; acc.z += w * xv.z; acc.w += w * xv.w;
    }
    short o[4] = {f2bf(acc.x * ws), f2bf(acc.y * ws), f2bf(acc.z * ws), f2bf(acc.w * ws)};
    *reinterpret_cast<int2*>(&pooled[(size_t)blk * HDIM + tid * 4]) =
        *reinterpret_cast<const int2*>(o);
}

// ---------------------------------------------------------------------------
// GEMM2: y = pooled @ Wp + bp. 1024^3. 64x64 tiles, 4 waves, dbuf + gll.
// ---------------------------------------------------------------------------
__global__ __launch_bounds__(256) void k_gemm2(
    const bf16s* __restrict__ pooled, const bf16s* __restrict__ wpt,
    const float* __restrict__ bp, float* __restrict__ y)
{
    __shared__ alignas(16) bf16s As[2][64 * 32];
    __shared__ alignas(16) bf16s Bs[2][64 * 32];
    const int tid = threadIdx.x;
    const int lane = tid & 63;
    const int wv = tid >> 6;
    const int wr = wv >> 1, wc = wv & 1;
    const int row0 = (blockIdx.x >> 4) * 64, col0 = (blockIdx.x & 15) * 64;
    const int c0 = lane & 15, khalf = lane >> 4;

    const int sr = wv * 16 + (lane >> 2);
    const int sj = (lane & 3) ^ ((sr >> 1) & 3);
    const int sdst = (wv * 16) * 32 + lane * 8;
    const bf16s* srcA = &pooled[(size_t)(row0 + sr) * 1024 + sj * 8];
    const bf16s* srcB = &wpt[(size_t)(col0 + sr) * 1024 + sj * 8];

    f32x4 acc[2][2] = {};

    gload_lds16(srcA, &As[0][sdst]);
    gload_lds16(srcB, &Bs[0][sdst]);
    __syncthreads();

    for (int t = 0; t < 32; ++t) {
        const int cur = t & 1;
        if (t < 31) {
            gload_lds16(srcA + (t + 1) * 32, &As[cur ^ 1][sdst]);
            gload_lds16(srcB + (t + 1) * 32, &Bs[cur ^ 1][sdst]);
        }
        #pragma unroll
        for (int mf = 0; mf < 2; ++mf) {
            int ra = wr * 32 + mf * 16 + c0;
            short8 av = *reinterpret_cast<const short8*>(
                &As[cur][ra * 32 + ((khalf ^ ((ra >> 1) & 3)) * 8)]);
            #pragma unroll
            for (int nf = 0; nf < 2; ++nf) {
                int rb = wc * 32 + nf * 16 + c0;
                short8 bv = *reinterpret_cast<const short8*>(
                    &Bs[cur][rb * 32 + ((khalf ^ ((rb >> 1) & 3)) * 8)]);
                acc[mf][nf] = __builtin_amdgcn_mfma_f32_16x16x32_bf16(av, bv, acc[mf][nf], 0, 0, 0);
            }
        }
        __syncthreads();
    }
    #pragma unroll
    for (int mf = 0; mf < 2; ++mf)
        #pragma unroll
        for (int nf = 0; nf < 2; ++nf)
            #pragma unroll
            for (int reg = 0; reg < 4; ++reg) {
                int grow = row0 + wr * 32 + mf * 16 + khalf * 4 + reg;
                int gcol = col0 + wc * 32 + nf * 16 + c0;
                y[(size_t)grow * 1024 + gcol] = acc[mf][nf][reg] + bp[gcol];
            }
}

// ---------------------------------------------------------------------------
// LayerNorm + ELU + present-mask.
// ---------------------------------------------------------------------------
__global__ void k_lnelu(const float* __restrict__ y, const float* __restrict__ ln_g,
                        const float* __restrict__ ln_b, const int* __restrict__ counts,
                        float* __restrict__ outp)
{
    const int row = blockIdx.x;
    const int k = row & 127;
    const int tid = threadIdx.x;

    float4 v = *reinterpret_cast<const float4*>(&y[(size_t)row * 1024 + tid * 4]);
    float s = v.x + v.y + v.z + v.w;
    float ss = v.x * v.x + v.y * v.y + v.z * v.z + v.w * v.w;
    #pragma unroll
    for (int off = 32; off; off >>= 1) { s += __shfl_xor(s, off); ss += __shfl_xor(ss, off); }

    __shared__ float sbuf[4], ssbuf[4];
    int wv = tid >> 6;
    if ((tid & 63) == 0) { sbuf[wv] = s; ssbuf[wv] = ss; }
    __syncthreads();
    s = sbuf[0] + sbuf[1] + sbuf[2] + sbuf[3];
    ss = ssbuf[0] + ssbuf[1] + ssbuf[2] + ssbuf[3];

    float mu = s * (1.f / 1024.f);
    float var = ss * (1.f / 1024.f) - mu * mu;
    float rstd = rsqrtf(var + 1e-5f);

    bool pres = false;
    #pragma unroll
    for (int bb = 0; bb < 8; ++bb) pres = pres || (counts[bb * NBLK + k] > 0);

    float4 g4 = *reinterpret_cast<const float4*>(&ln_g[tid * 4]);
    float4 b4 = *reinterpret_cast<const float4*>(&ln_b[tid * 4]);
    float vals[4] = {v.x, v.y, v.z, v.w};
    float gs[4] = {g4.x, g4.y, g4.z, g4.w};
    float bs[4] = {b4.x, b4.y, b4.z, b4.w};
    float4 o;
    float* op = &o.x;
    #pragma unroll
    for (int j = 0; j < 4; ++j) {
        float t = (vals[j] - mu) * rstd * gs[j] + bs[j];
        t = (t > 0.f) ? t : expm1f(t);
        op[j] = pres ? t : 0.f;
    }
    *reinterpret_cast<float4*>(&outp[(size_t)row * 1024 + tid * 4]) = o;
}

// ---------------------------------------------------------------------------
extern "C" void kernel_launch(void* const* d_in, const int* in_sizes, int n_in,
                              void* d_out, int out_size, void* d_ws, size_t ws_size,
                              hipStream_t stream)
{
    const float* x      = (const float*)d_in[0];
    const int*   ct     = (const int*)d_in[1];
    const int*   bids   = (const int*)d_in[2];
    const unsigned char* pad = (const unsigned char*)d_in[3];
    const float* W1     = (const float*)d_in[4];
    const float* b1     = (const float*)d_in[5];
    const float* W2     = (const float*)d_in[6];
    const float* b2     = (const float*)d_in[7];
    const float* ct_emb = (const float*)d_in[8];
    const float* Wp     = (const float*)d_in[9];
    const float* bp     = (const float*)d_in[10];
    const float* ln_g   = (const float*)d_in[11];
    const float* ln_b   = (const float*)d_in[12];
    float* outF = (float*)d_out;

    char* ws = (char*)d_ws;
    bf16s* w1t    = (bf16s*)(ws + 0);          //  1,048,576
    bf16s* wpt    = (bf16s*)(ws + 1048576);    //  2,097,152 -> 3,145,728
    float* gate   = (float*)(ws + 3145728);    //    131,072 -> 3,276,800
    float* part   = (float*)(ws + 3276800);    //    524,288 -> 3,801,088
    float* mblk   = (float*)(ws + 3801088);
    float* wscal  = (float*)(ws + 3805184);
    int*   counts = (int*)  (ws + 3809280);
    int*   lists  = (int*)  (ws + 3813376);    //  1,048,576 -> 4,861,952
    bf16s* pooled = (bf16s*)(ws + 4861952);    //  2,097,152 -> 6,959,104
    float* ybuf   = (float*)(ws + 6959104);    //  4,194,304 -> 11,153,408
    bf16s* xb     = (bf16s*)(ws + 11153408);   // 67,108,864 -> 78,262,272
    const int use_xb = (ws_size >= 78262272ull) ? 1 : 0;

    k_tcvt2<<<dim3(16, 24), 256, 0, stream>>>(W1, Wp, w1t, wpt);
    if (use_xb) {
        k_xcvt<<<2048, 256, 0, stream>>>(x, xb);
        k_gemm_g<<<1024, 256, 0, stream>>>(xb, w1t, b1, W2, part);
    } else {
        k_gemm_h<<<1024, 256, 0, stream>>>(x, w1t, b1, W2, part);
    }
    k_gate_sum<<<32, 256, 0, stream>>>(part, b2, gate);
    k_blocks<<<1024, 64, 0, stream>>>(bids, pad, gate, ct, ct_emb, counts, mblk, wscal,
                                      lists, outF + (size_t)8 * NBLK * HDIM);
    k_pool<<<1024, 256, 0, stream>>>(x, xb, use_xb, gate, lists, counts, mblk, wscal, pooled);
    k_gemm2<<<256, 256, 0, stream>>>(pooled, wpt, bp, ybuf);
    k_lnelu<<<1024, 256, 0, stream>>>(ybuf, ln_g, ln_b, counts, outF);
}

// Round 6
// 154.237 us; speedup vs baseline: 1.0352x; 1.0352x over previous
//
#include <hip/hip_runtime.h>

// (B,N,H,NB,NCT) = (8,4096,1024,128,33), H/2 = 512
#define NTOK 4096
#define HDIM 1024
#define HHALF 512
#define NBLK 128
#define CAP 256
#define XELEMS 33554432ull   // 8*4096*1024

typedef __attribute__((ext_vector_type(8))) short short8;
typedef __attribute__((ext_vector_type(4))) float f32x4;
typedef short bf16s;

__device__ __forceinline__ short f2bf(float f) {
    unsigned u = __builtin_bit_cast(unsigned, f);
    u = (u + 0x7fffu + ((u >> 16) & 1u)) >> 16;   // RNE
    return (short)u;
}
__device__ __forceinline__ void gload_lds16(const void* g, void* l) {
    __builtin_amdgcn_global_load_lds(
        (const __attribute__((address_space(1))) unsigned int*)g,
        (__attribute__((address_space(3))) unsigned int*)l, 16, 0, 0);
}
__device__ __forceinline__ float fast_tanh(float v) {
    float e = __expf(2.0f * v);
    return 1.0f - 2.0f / (e + 1.0f);
}

// ---------------------------------------------------------------------------
// x (f32) -> xb (bf16), grid-stride, vectorized. Memory-bound.
// ---------------------------------------------------------------------------
__global__ void k_xcvt(const float* __restrict__ in, bf16s* __restrict__ out) {
    for (size_t i = ((size_t)blockIdx.x * 256 + threadIdx.x) * 8; i < XELEMS;
         i += (size_t)gridDim.x * 256 * 8) {
        float4 a = *reinterpret_cast<const float4*>(&in[i]);
        float4 b = *reinterpret_cast<const float4*>(&in[i + 4]);
        short h[8] = {f2bf(a.x), f2bf(a.y), f2bf(a.z), f2bf(a.w),
                      f2bf(b.x), f2bf(b.y), f2bf(b.z), f2bf(b.w)};
        *reinterpret_cast<int4*>(&out[i]) = *reinterpret_cast<const int4*>(h);
    }
}

// ---------------------------------------------------------------------------
// Tiled transpose+convert for both weights in one launch.
// ---------------------------------------------------------------------------
__global__ void k_tcvt2(const float* __restrict__ W1, const float* __restrict__ Wp,
                        bf16s* __restrict__ w1t, bf16s* __restrict__ wpt) {
    __shared__ float tile[64][65];
    const int by = blockIdx.y;
    const float* in = (by < 8) ? W1 : Wp;
    bf16s* out = (by < 8) ? w1t : wpt;
    const int Nc = (by < 8) ? HHALF : HDIM;
    const int n0 = ((by < 8) ? by : (by - 8)) * 64;
    const int k0 = blockIdx.x * 64;
    const int tx = threadIdx.x & 63, ty = threadIdx.x >> 6;
    #pragma unroll
    for (int i = 0; i < 16; ++i) {
        int r = ty + i * 4;
        tile[r][tx] = in[(size_t)(k0 + r) * Nc + n0 + tx];
    }
    __syncthreads();
    #pragma unroll
    for (int i = 0; i < 16; ++i) {
        int r = ty + i * 4;
        out[(size_t)(n0 + r) * 1024 + k0 + tx] = f2bf(tile[tx][r]);
    }
}

// ---------------------------------------------------------------------------
// Gate GEMM — counted-vmcnt schedule (T4): BK=64, double-buffered LDS,
// raw s_barrier, prefetch gll stays in flight across barriers (vmcnt(8),
// never 0 in-loop). 128x128 tile, 4 waves (2x2), acc[4][4].
// LDS rows 64 shorts (128B); chunk-XOR swizzle j^(row&7) both-sides.
// ---------------------------------------------------------------------------
__global__ __launch_bounds__(256, 2) void k_gemm_g(
    const bf16s* __restrict__ xb, const bf16s* __restrict__ w1t,
    const float* __restrict__ b1, const float* __restrict__ w2,
    float* __restrict__ partial)
{
    __shared__ alignas(16) bf16s As[2][128 * 64];
    __shared__ alignas(16) bf16s Bs[2][128 * 64];
    __shared__ float gp[2][128];

    const int tid = threadIdx.x;
    const int lane = tid & 63;
    const int wv = tid >> 6;
    const int wr = wv >> 1, wc = wv & 1;
    const int phys = blockIdx.x;
    const int logical = (phys & 7) * 128 + (phys >> 3);   // 1024 = 8*128 bijective
    const int row0 = (logical >> 2) * 128;
    const int col0 = (logical & 3) * 128;
    const int c0 = lane & 15, khalf = lane >> 4;

    // staging: wave wv, q=0..3 -> row wv*32+q*8+(lane>>3), source chunk (lane&7)^(lane>>3)
    const int srow = wv * 32 + (lane >> 3);
    const int sj   = (lane & 7) ^ (lane >> 3);
    const bf16s* aSrc = &xb [(size_t)(row0 + srow) * HDIM + sj * 8];
    const bf16s* bSrc = &w1t[(size_t)(col0 + srow) * HDIM + sj * 8];
    const int sdst = (wv * 256 + lane) * 8;   // + q*512 shorts

    f32x4 acc[4][4] = {};

    // prologue: issue tile 0 (8 gll in flight)
    #pragma unroll
    for (int q = 0; q < 4; ++q) {
        gload_lds16(aSrc + q * 8 * HDIM, &As[0][sdst + q * 512]);
        gload_lds16(bSrc + q * 8 * HDIM, &Bs[0][sdst + q * 512]);
    }

    for (int t = 0; t < 16; ++t) {
        const int cur = t & 1;
        if (t < 15) {
            const int koff = (t + 1) * 64;
            #pragma unroll
            for (int q = 0; q < 4; ++q) {
                gload_lds16(aSrc + q * 8 * HDIM + koff, &As[cur ^ 1][sdst + q * 512]);
                gload_lds16(bSrc + q * 8 * HDIM + koff, &Bs[cur ^ 1][sdst + q * 512]);
            }
            asm volatile("s_waitcnt vmcnt(8)" ::: "memory");  // tile t complete; t+1 in flight
        } else {
            asm volatile("s_waitcnt vmcnt(0)" ::: "memory");
        }
        __builtin_amdgcn_s_barrier();
        __builtin_amdgcn_sched_barrier(0);

        #pragma unroll
        for (int s = 0; s < 2; ++s) {
            short8 av[4], bv[4];
            #pragma unroll
            for (int mf = 0; mf < 4; ++mf) {
                int ra = wr * 64 + mf * 16 + c0;
                int ka = (s * 4 + khalf) ^ (ra & 7);
                av[mf] = *reinterpret_cast<const short8*>(&As[cur][ra * 64 + ka * 8]);
            }
            #pragma unroll
            for (int nf = 0; nf < 4; ++nf) {
                int rb = wc * 64 + nf * 16 + c0;
                int kb = (s * 4 + khalf) ^ (rb & 7);
                bv[nf] = *reinterpret_cast<const short8*>(&Bs[cur][rb * 64 + kb * 8]);
            }
            #pragma unroll
            for (int nf = 0; nf < 4; ++nf)
                #pragma unroll
                for (int mf = 0; mf < 4; ++mf)
                    acc[mf][nf] = __builtin_amdgcn_mfma_f32_16x16x32_bf16(av[mf], bv[nf], acc[mf][nf], 0, 0, 0);
        }

        asm volatile("s_waitcnt lgkmcnt(0)" ::: "memory");
        __builtin_amdgcn_sched_barrier(0);                 // rule 18: pin MFMA/ds_read
        __builtin_amdgcn_s_barrier();                      // buf[cur] free for t+2 gll
    }

    // epilogue: per-row partial dot of tanh(h)*W2 over this wave's 64 cols
    float b1v[4], w2v[4];
    #pragma unroll
    for (int nf = 0; nf < 4; ++nf) {
        int gc = col0 + wc * 64 + nf * 16 + c0;
        b1v[nf] = b1[gc];
        w2v[nf] = w2[gc];
    }
    #pragma unroll
    for (int mf = 0; mf < 4; ++mf) {
        #pragma unroll
        for (int reg = 0; reg < 4; ++reg) {
            float s = 0.f;
            #pragma unroll
            for (int nf = 0; nf < 4; ++nf)
                s += fast_tanh(acc[mf][nf][reg] + b1v[nf]) * w2v[nf];
            s += __shfl_xor(s, 1); s += __shfl_xor(s, 2);
            s += __shfl_xor(s, 4); s += __shfl_xor(s, 8);
            if (c0 == 0) gp[wc][wr * 64 + mf * 16 + khalf * 4 + reg] = s;
        }
    }
    __syncthreads();
    if (tid < 128)
        partial[(size_t)(logical & 3) * 32768 + row0 + tid] = gp[0][tid] + gp[1][tid];
}

// ---------------------------------------------------------------------------
// FALLBACK gate GEMM (R4 path, f32 x) — used only if ws can't hold xb.
// ---------------------------------------------------------------------------
__global__ __launch_bounds__(256, 3) void k_gemm_h(
    const float* __restrict__ x, const bf16s* __restrict__ w1t,
    const float* __restrict__ b1, const float* __restrict__ w2,
    float* __restrict__ partial)
{
    __shared__ alignas(16) bf16s As[128 * 36];
    __shared__ alignas(16) bf16s Bs[128 * 32];
    __shared__ float gp[2][128];

    const int tid = threadIdx.x;
    const int lane = tid & 63;
    const int wv = tid >> 6;
    const int wr = wv >> 1, wc = wv & 1;
    const int phys = blockIdx.x;
    const int logical = (phys & 7) * 128 + (phys >> 3);
    const int row0 = (logical >> 2) * 128;
    const int col0 = (logical & 3) * 128;
    const int c0 = lane & 15, khalf = lane >> 4;

    const int ar = tid >> 1, ah = tid & 1;
    const float* xsrc = &x[(size_t)(row0 + ar) * HDIM + ah * 16];
    const int brow = wv * 32 + (lane >> 2);
    const int bj = lane & 3;

    f32x4 acc[4][4] = {};
    float4 pa0 = *reinterpret_cast<const float4*>(xsrc);
    float4 pa1 = *reinterpret_cast<const float4*>(xsrc + 4);
    float4 pa2 = *reinterpret_cast<const float4*>(xsrc + 8);
    float4 pa3 = *reinterpret_cast<const float4*>(xsrc + 12);

    for (int t = 0; t < 32; ++t) {
        const int kt = t * 32;
        __syncthreads();
        {
            short h[16] = {f2bf(pa0.x), f2bf(pa0.y), f2bf(pa0.z), f2bf(pa0.w),
                           f2bf(pa1.x), f2bf(pa1.y), f2bf(pa1.z), f2bf(pa1.w),
                           f2bf(pa2.x), f2bf(pa2.y), f2bf(pa2.z), f2bf(pa2.w),
                           f2bf(pa3.x), f2bf(pa3.y), f2bf(pa3.z), f2bf(pa3.w)};
            *reinterpret_cast<int4*>(&As[ar * 36 + ah * 16]) =
                *reinterpret_cast<const int4*>(&h[0]);
            *reinterpret_cast<int4*>(&As[ar * 36 + ah * 16 + 8]) =
                *reinterpret_cast<const int4*>(&h[8]);
        }
        #pragma unroll
        for (int q = 0; q < 2; ++q) {
            int r = brow + q * 16;
            int j = bj ^ ((r >> 1) & 3);
            gload_lds16(&w1t[(size_t)(col0 + r) * HDIM + kt + j * 8],
                        &Bs[(wv * 32 + q * 16) * 32 + lane * 8]);
        }
        __syncthreads();
        if (t < 31) {
            pa0 = *reinterpret_cast<const float4*>(xsrc + kt + 32);
            pa1 = *reinterpret_cast<const float4*>(xsrc + kt + 36);
            pa2 = *reinterpret_cast<const float4*>(xsrc + kt + 40);
            pa3 = *reinterpret_cast<const float4*>(xsrc + kt + 44);
        }
        const int kk = khalf * 8;
        short8 av[4];
        #pragma unroll
        for (int mf = 0; mf < 4; ++mf)
            av[mf] = *reinterpret_cast<const short8*>(
                &As[(wr * 64 + mf * 16 + c0) * 36 + kk]);
        #pragma unroll
        for (int nf = 0; nf < 4; ++nf) {
            int rb = wc * 64 + nf * 16 + c0;
            short8 bv = *reinterpret_cast<const short8*>(
                &Bs[rb * 32 + ((khalf ^ ((rb >> 1) & 3)) * 8)]);
            #pragma unroll
            for (int mf = 0; mf < 4; ++mf)
                acc[mf][nf] = __builtin_amdgcn_mfma_f32_16x16x32_bf16(av[mf], bv, acc[mf][nf], 0, 0, 0);
        }
    }
    float b1v[4], w2v[4];
    #pragma unroll
    for (int nf = 0; nf < 4; ++nf) {
        int gc = col0 + wc * 64 + nf * 16 + c0;
        b1v[nf] = b1[gc];
        w2v[nf] = w2[gc];
    }
    #pragma unroll
    for (int mf = 0; mf < 4; ++mf) {
        #pragma unroll
        for (int reg = 0; reg < 4; ++reg) {
            float s = 0.f;
            #pragma unroll
            for (int nf = 0; nf < 4; ++nf)
                s += fast_tanh(acc[mf][nf][reg] + b1v[nf]) * w2v[nf];
            s += __shfl_xor(s, 1); s += __shfl_xor(s, 2);
            s += __shfl_xor(s, 4); s += __shfl_xor(s, 8);
            if (c0 == 0) gp[wc][wr * 64 + mf * 16 + khalf * 4 + reg] = s;
        }
    }
    __syncthreads();
    if (tid < 128)
        partial[(size_t)(logical & 3) * 32768 + row0 + tid] = gp[0][tid] + gp[1][tid];
}

// ---------------------------------------------------------------------------
__global__ void k_gate_sum(const float* __restrict__ partial, const float* __restrict__ b2,
                           float* __restrict__ gate) {
    int i = (blockIdx.x * 256 + threadIdx.x) * 4;
    float4 p0 = *reinterpret_cast<const float4*>(&partial[i]);
    float4 p1 = *reinterpret_cast<const float4*>(&partial[32768 + i]);
    float4 p2 = *reinterpret_cast<const float4*>(&partial[65536 + i]);
    float4 p3 = *reinterpret_cast<const float4*>(&partial[98304 + i]);
    float bb = b2[0];
    float4 o = {p0.x + p1.x + p2.x + p3.x + bb, p0.y + p1.y + p2.y + p3.y + bb,
                p0.z + p1.z + p2.z + p3.z + bb, p0.w + p1.w + p2.w + p3.w + bb};
    *reinterpret_cast<float4*>(&gate[i]) = o;
}

// ---------------------------------------------------------------------------
// Single-pass per-(b,block): online-softmax stats + ordered member lists.
// ---------------------------------------------------------------------------
__global__ void k_blocks(const int* __restrict__ block_ids, const unsigned char* __restrict__ pad,
                         const float* __restrict__ gate, const int* __restrict__ ct,
                         const float* __restrict__ ct_emb,
                         int* __restrict__ counts, float* __restrict__ mblk,
                         float* __restrict__ wscale, int* __restrict__ lists,
                         float* __restrict__ out_hasb)
{
    const int blk = blockIdx.x;
    const int b = blk >> 7, k = blk & 127;
    const int lane = threadIdx.x;
    const int base = b * NTOK;
    const int lbase = blk * CAP;
    const unsigned long long ltmask = (1ull << lane) - 1ull;

    float m = -__builtin_inff();
    float s = 0.f;
    int pos = 0;
    for (int t0 = 0; t0 < NTOK; t0 += 64) {
        int t = t0 + lane;
        bool mt = (block_ids[base + t] == k) && (pad[base + t] == 0);
        float g = gate[base + t];
        unsigned long long mask = __ballot(mt);
        if (mt) {
            int my = pos + __popcll(mask & ltmask);
            if (my < CAP) lists[lbase + my] = t;
            float mn = fmaxf(m, g);
            s = s * __expf(m - mn) + __expf(g - mn);
            m = mn;
        }
        pos += __popcll(mask);
    }
    #pragma unroll
    for (int off = 1; off < 64; off <<= 1) {
        float om = __shfl_xor(m, off);
        float os = __shfl_xor(s, off);
        float mn = fmaxf(m, om);
        float sa = (m == -__builtin_inff()) ? 0.f : s * __expf(m - mn);
        float sb = (om == -__builtin_inff()) ? 0.f : os * __expf(om - mn);
        s = sa + sb;
        m = mn;
    }
    if (lane == 0) {
        counts[blk] = pos;
        mblk[blk] = (pos > 0) ? m : 0.f;
        float mod = 1.0f + 0.1f * ct_emb[ct[b] * NBLK + k];
        wscale[blk] = (pos > 0 && s > 0.f) ? (mod / fmaxf(s, 1e-30f)) : 0.f;
        out_hasb[blk] = (pos > 0) ? 1.f : 0.f;
    }
}

// ---------------------------------------------------------------------------
// Pooling from bf16 xb (or f32 x fallback).
// ---------------------------------------------------------------------------
__global__ void k_pool(const float* __restrict__ x, const bf16s* __restrict__ xb, int use_bf,
                       const float* __restrict__ gate,
                       const int* __restrict__ lists, const int* __restrict__ counts,
                       const float* __restrict__ mblk, const float* __restrict__ wscale,
                       bf16s* __restrict__ pooled)
{
    const int blk = blockIdx.x;
    const int b = blk >> 7;
    const int tid = threadIdx.x;
    const int base = b * NTOK;
    const int cnt = min(counts[blk], CAP);
    const int lbase = blk * CAP;
    const float m = mblk[blk], ws = wscale[blk];

    float4 acc = {0.f, 0.f, 0.f, 0.f};
    for (int i = 0; i < cnt; ++i) {
        int n = lists[lbase + i];
        float w = __expf(gate[base + n] - m);
        float4 xv;
        if (use_bf) {
            int2 rv = *reinterpret_cast<const int2*>(&xb[(size_t)(base + n) * HDIM + tid * 4]);
            short s4[4];
            *reinterpret_cast<int2*>(s4) = rv;
            unsigned u0 = ((unsigned)(unsigned short)s4[0]) << 16;
            unsigned u1 = ((unsigned)(unsigned short)s4[1]) << 16;
            unsigned u2 = ((unsigned)(unsigned short)s4[2]) << 16;
            unsigned u3 = ((unsigned)(unsigned short)s4[3]) << 16;
            xv.x = __builtin_bit_cast(float, u0); xv.y = __builtin_bit_cast(float, u1);
            xv.z = __builtin_bit_cast(float, u2); xv.w = __builtin_bit_cast(float, u3);
        } else {
            xv = *reinterpret_cast<const float4*>(&x[(size_t)(base + n) * HDIM + tid * 4]);
        }
        acc.x += w * xv.x; acc.y += w * xv.y; acc.z += w * xv.z; acc.w += w * xv.w;
    }
    short o[4] = {f2bf(acc.x * ws), f2bf(acc.y * ws), f2bf(acc.z * ws), f2bf(acc.w * ws)};
    *reinterpret_cast<int2*>(&pooled[(size_t)blk * HDIM + tid * 4]) =
        *reinterpret_cast<const int2*>(o);
}

// ---------------------------------------------------------------------------
// GEMM2: y = pooled @ Wp + bp. 1024^3. 64x64 tiles, 4 waves, dbuf + gll,
// counted-vmcnt schedule (vmcnt(2) in-loop, raw barriers).
// ---------------------------------------------------------------------------
__global__ __launch_bounds__(256) void k_gemm2(
    const bf16s* __restrict__ pooled, const bf16s* __restrict__ wpt,
    const float* __restrict__ bp, float* __restrict__ y)
{
    __shared__ alignas(16) bf16s As[2][64 * 32];
    __shared__ alignas(16) bf16s Bs[2][64 * 32];
    const int tid = threadIdx.x;
    const int lane = tid & 63;
    const int wv = tid >> 6;
    const int wr = wv >> 1, wc = wv & 1;
    const int row0 = (blockIdx.x >> 4) * 64, col0 = (blockIdx.x & 15) * 64;
    const int c0 = lane & 15, khalf = lane >> 4;

    const int sr = wv * 16 + (lane >> 2);
    const int sj = (lane & 3) ^ ((sr >> 1) & 3);
    const int sdst = (wv * 16) * 32 + lane * 8;
    const bf16s* srcA = &pooled[(size_t)(row0 + sr) * 1024 + sj * 8];
    const bf16s* srcB = &wpt[(size_t)(col0 + sr) * 1024 + sj * 8];

    f32x4 acc[2][2] = {};

    gload_lds16(srcA, &As[0][sdst]);
    gload_lds16(srcB, &Bs[0][sdst]);

    for (int t = 0; t < 32; ++t) {
        const int cur = t & 1;
        if (t < 31) {
            gload_lds16(srcA + (t + 1) * 32, &As[cur ^ 1][sdst]);
            gload_lds16(srcB + (t + 1) * 32, &Bs[cur ^ 1][sdst]);
            asm volatile("s_waitcnt vmcnt(2)" ::: "memory");
        } else {
            asm volatile("s_waitcnt vmcnt(0)" ::: "memory");
        }
        __builtin_amdgcn_s_barrier();
        __builtin_amdgcn_sched_barrier(0);
        #pragma unroll
        for (int mf = 0; mf < 2; ++mf) {
            int ra = wr * 32 + mf * 16 + c0;
            short8 av = *reinterpret_cast<const short8*>(
                &As[cur][ra * 32 + ((khalf ^ ((ra >> 1) & 3)) * 8)]);
            #pragma unroll
            for (int nf = 0; nf < 2; ++nf) {
                int rb = wc * 32 + nf * 16 + c0;
                short8 bv = *reinterpret_cast<const short8*>(
                    &Bs[cur][rb * 32 + ((khalf ^ ((rb >> 1) & 3)) * 8)]);
                acc[mf][nf] = __builtin_amdgcn_mfma_f32_16x16x32_bf16(av, bv, acc[mf][nf], 0, 0, 0);
            }
        }
        asm volatile("s_waitcnt lgkmcnt(0)" ::: "memory");
        __builtin_amdgcn_sched_barrier(0);
        __builtin_amdgcn_s_barrier();
    }
    #pragma unroll
    for (int mf = 0; mf < 2; ++mf)
        #pragma unroll
        for (int nf = 0; nf < 2; ++nf)
            #pragma unroll
            for (int reg = 0; reg < 4; ++reg) {
                int grow = row0 + wr * 32 + mf * 16 + khalf * 4 + reg;
                int gcol = col0 + wc * 32 + nf * 16 + c0;
                y[(size_t)grow * 1024 + gcol] = acc[mf][nf][reg] + bp[gcol];
            }
}

// ---------------------------------------------------------------------------
// LayerNorm + ELU + present-mask.
// ---------------------------------------------------------------------------
__global__ void k_lnelu(const float* __restrict__ y, const float* __restrict__ ln_g,
                        const float* __restrict__ ln_b, const int* __restrict__ counts,
                        float* __restrict__ outp)
{
    const int row = blockIdx.x;
    const int k = row & 127;
    const int tid = threadIdx.x;

    float4 v = *reinterpret_cast<const float4*>(&y[(size_t)row * 1024 + tid * 4]);
    float s = v.x + v.y + v.z + v.w;
    float ss = v.x * v.x + v.y * v.y + v.z * v.z + v.w * v.w;
    #pragma unroll
    for (int off = 32; off; off >>= 1) { s += __shfl_xor(s, off); ss += __shfl_xor(ss, off); }

    __shared__ float sbuf[4], ssbuf[4];
    int wv = tid >> 6;
    if ((tid & 63) == 0) { sbuf[wv] = s; ssbuf[wv] = ss; }
    __syncthreads();
    s = sbuf[0] + sbuf[1] + sbuf[2] + sbuf[3];
    ss = ssbuf[0] + ssbuf[1] + ssbuf[2] + ssbuf[3];

    float mu = s * (1.f / 1024.f);
    float var = ss * (1.f / 1024.f) - mu * mu;
    float rstd = rsqrtf(var + 1e-5f);

    bool pres = false;
    #pragma unroll
    for (int bb = 0; bb < 8; ++bb) pres = pres || (counts[bb * NBLK + k] > 0);

    float4 g4 = *reinterpret_cast<const float4*>(&ln_g[tid * 4]);
    float4 b4 = *reinterpret_cast<const float4*>(&ln_b[tid * 4]);
    float vals[4] = {v.x, v.y, v.z, v.w};
    float gs[4] = {g4.x, g4.y, g4.z, g4.w};
    float bs[4] = {b4.x, b4.y, b4.z, b4.w};
    float4 o;
    float* op = &o.x;
    #pragma unroll
    for (int j = 0; j < 4; ++j) {
        float t = (vals[j] - mu) * rstd * gs[j] + bs[j];
        t = (t > 0.f) ? t : expm1f(t);
        op[j] = pres ? t : 0.f;
    }
    *reinterpret_cast<float4*>(&outp[(size_t)row * 1024 + tid * 4]) = o;
}

// ---------------------------------------------------------------------------
extern "C" void kernel_launch(void* const* d_in, const int* in_sizes, int n_in,
                              void* d_out, int out_size, void* d_ws, size_t ws_size,
                              hipStream_t stream)
{
    const float* x      = (const float*)d_in[0];
    const int*   ct     = (const int*)d_in[1];
    const int*   bids   = (const int*)d_in[2];
    const unsigned char* pad = (const unsigned char*)d_in[3];
    const float* W1     = (const float*)d_in[4];
    const float* b1     = (const float*)d_in[5];
    const float* W2     = (const float*)d_in[6];
    const float* b2     = (const float*)d_in[7];
    const float* ct_emb = (const float*)d_in[8];
    const float* Wp     = (const float*)d_in[9];
    const float* bp     = (const float*)d_in[10];
    const float* ln_g   = (const float*)d_in[11];
    const float* ln_b   = (const float*)d_in[12];
    float* outF = (float*)d_out;

    char* ws = (char*)d_ws;
    bf16s* w1t    = (bf16s*)(ws + 0);          //  1,048,576
    bf16s* wpt    = (bf16s*)(ws + 1048576);    //  2,097,152 -> 3,145,728
    float* gate   = (float*)(ws + 3145728);    //    131,072 -> 3,276,800
    float* part   = (float*)(ws + 3276800);    //    524,288 -> 3,801,088
    float* mblk   = (float*)(ws + 3801088);
    float* wscal  = (float*)(ws + 3805184);
    int*   counts = (int*)  (ws + 3809280);
    int*   lists  = (int*)  (ws + 3813376);    //  1,048,576 -> 4,861,952
    bf16s* pooled = (bf16s*)(ws + 4861952);    //  2,097,152 -> 6,959,104
    float* ybuf   = (float*)(ws + 6959104);    //  4,194,304 -> 11,153,408
    bf16s* xb     = (bf16s*)(ws + 11153408);   // 67,108,864 -> 78,262,272
    const int use_xb = (ws_size >= 78262272ull) ? 1 : 0;

    k_tcvt2<<<dim3(16, 24), 256, 0, stream>>>(W1, Wp, w1t, wpt);
    if (use_xb) {
        k_xcvt<<<2048, 256, 0, stream>>>(x, xb);
        k_gemm_g<<<1024, 256, 0, stream>>>(xb, w1t, b1, W2, part);
    } else {
        k_gemm_h<<<1024, 256, 0, stream>>>(x, w1t, b1, W2, part);
    }
    k_gate_sum<<<32, 256, 0, stream>>>(part, b2, gate);
    k_blocks<<<1024, 64, 0, stream>>>(bids, pad, gate, ct, ct_emb, counts, mblk, wscal,
                                      lists, outF + (size_t)8 * NBLK * HDIM);
    k_pool<<<1024, 256, 0, stream>>>(x, xb, use_xb, gate, lists, counts, mblk, wscal, pooled);
    k_gemm2<<<256, 256, 0, stream>>>(pooled, wpt, bp, ybuf);
    k_lnelu<<<1024, 256, 0, stream>>>(ybuf, ln_g, ln_b, counts, outF);
}

// Round 7
// 151.751 us; speedup vs baseline: 1.0521x; 1.0164x over previous
//
#include <hip/hip_runtime.h>

// (B,N,H,NB,NCT) = (8,4096,1024,128,33), H/2 = 512
#define NTOK 4096
#define HDIM 1024
#define HHALF 512
#define NBLK 128
#define CAP 256

typedef __attribute__((ext_vector_type(8))) short short8;
typedef __attribute__((ext_vector_type(4))) float f32x4;
typedef short bf16s;

__device__ __forceinline__ short f2bf(float f) {
    unsigned u = __builtin_bit_cast(unsigned, f);
    u = (u + 0x7fffu + ((u >> 16) & 1u)) >> 16;   // RNE
    return (short)u;
}
__device__ __forceinline__ void gload_lds16(const void* g, void* l) {
    __builtin_amdgcn_global_load_lds(
        (const __attribute__((address_space(1))) unsigned int*)g,
        (__attribute__((address_space(3))) unsigned int*)l, 16, 0, 0);
}
__device__ __forceinline__ float fast_tanh(float v) {
    float e = __expf(2.0f * v);
    return 1.0f - 2.0f / (e + 1.0f);
}

// ---------------------------------------------------------------------------
// Tiled transpose+convert for both weights in one launch.
// ---------------------------------------------------------------------------
__global__ void k_tcvt2(const float* __restrict__ W1, const float* __restrict__ Wp,
                        bf16s* __restrict__ w1t, bf16s* __restrict__ wpt) {
    __shared__ float tile[64][65];
    const int by = blockIdx.y;
    const float* in = (by < 8) ? W1 : Wp;
    bf16s* out = (by < 8) ? w1t : wpt;
    const int Nc = (by < 8) ? HHALF : HDIM;
    const int n0 = ((by < 8) ? by : (by - 8)) * 64;
    const int k0 = blockIdx.x * 64;
    const int tx = threadIdx.x & 63, ty = threadIdx.x >> 6;
    #pragma unroll
    for (int i = 0; i < 16; ++i) {
        int r = ty + i * 4;
        tile[r][tx] = in[(size_t)(k0 + r) * Nc + n0 + tx];
    }
    __syncthreads();
    #pragma unroll
    for (int i = 0; i < 16; ++i) {
        int r = ty + i * 4;
        out[(size_t)(n0 + r) * 1024 + k0 + tx] = f2bf(tile[tx][r]);
    }
}

// ---------------------------------------------------------------------------
// Gate GEMM with INLINE f32->bf16 A-conversion (no xcvt pass, no xb buffer).
// partial[ct][row] = sum over col-tile ct's 128 cols of tanh(h+b1)*W2.
// 128x128 tile, BK=32, 4 waves (2x2), acc[4][4]. Counted-vmcnt dbuf schedule
// (R6-proven skeleton): issue 6 gll for t+1, vmcnt(6) -> tile t ready, raw
// barriers, lgkmcnt(0)+sched_barrier trailing fence. T5 setprio around MFMA.
// A: f32 LDS rows of 32 floats (8 chunks of 16B), chunk slot = j^(row&7).
// B: bf16 LDS rows of 32 bf16 (4 chunks), slot = j^((row>>1)&3) (2-way max).
// LDS 49KB -> 3 wg/CU (12 waves/CU).
// ---------------------------------------------------------------------------
__global__ __launch_bounds__(256, 3) void k_gemm_gf(
    const float* __restrict__ x, const bf16s* __restrict__ w1t,
    const float* __restrict__ b1, const float* __restrict__ w2,
    float* __restrict__ partial)
{
    __shared__ alignas(16) float As[2][128 * 32];   // 16KB per buf
    __shared__ alignas(16) bf16s Bs[2][128 * 32];   //  8KB per buf
    __shared__ float gp[2][128];

    const int tid = threadIdx.x;
    const int lane = tid & 63;
    const int wv = tid >> 6;
    const int wr = wv >> 1, wc = wv & 1;
    const int phys = blockIdx.x;
    const int logical = (phys & 7) * 128 + (phys >> 3);   // 1024 = 8*128 bijective
    const int row0 = (logical >> 2) * 128;
    const int col0 = (logical & 3) * 128;
    const int c0 = lane & 15, khalf = lane >> 4;

    // A staging: call q=0..3 covers rows wv*32+q*8+(lane>>3); src chunk pre-swizzled
    const int aRow = wv * 32 + (lane >> 3);
    const int aj = (lane & 7) ^ ((lane >> 3) & 7);
    const float* aSrc = &x[(size_t)(row0 + aRow) * HDIM + aj * 4];
    const int adst = wv * 1024 + lane * 4;            // float idx; + q*256

    // B staging: call q=0..1 covers rows wv*32+q*16+(lane>>2)
    const int bRow = wv * 32 + (lane >> 2);
    const int bj = (lane & 3) ^ ((lane >> 3) & 3);
    const bf16s* bSrc = &w1t[(size_t)(col0 + bRow) * HDIM + bj * 8];
    const int bdst = wv * 1024 + lane * 8;            // short idx; + q*512

    f32x4 acc[4][4] = {};

    // prologue: tile 0 (6 gll in flight)
    #pragma unroll
    for (int q = 0; q < 4; ++q)
        gload_lds16(aSrc + q * 8 * HDIM, &As[0][adst + q * 256]);
    #pragma unroll
    for (int q = 0; q < 2; ++q)
        gload_lds16(bSrc + q * 16 * HDIM, &Bs[0][bdst + q * 512]);

    for (int t = 0; t < 32; ++t) {
        const int cur = t & 1;
        if (t < 31) {
            const int ko = (t + 1) * 32;
            #pragma unroll
            for (int q = 0; q < 4; ++q)
                gload_lds16(aSrc + q * 8 * HDIM + ko, &As[cur ^ 1][adst + q * 256]);
            #pragma unroll
            for (int q = 0; q < 2; ++q)
                gload_lds16(bSrc + q * 16 * HDIM + ko, &Bs[cur ^ 1][bdst + q * 512]);
            asm volatile("s_waitcnt vmcnt(6)" ::: "memory");  // tile t complete
        } else {
            asm volatile("s_waitcnt vmcnt(0)" ::: "memory");
        }
        __builtin_amdgcn_s_barrier();
        __builtin_amdgcn_sched_barrier(0);

        // read f32 A fragments, convert to bf16 in regs; read bf16 B fragments
        short8 av[4], bv[4];
        #pragma unroll
        for (int mf = 0; mf < 4; ++mf) {
            int ra = wr * 64 + mf * 16 + c0;
            f32x4 lo = *reinterpret_cast<const f32x4*>(
                &As[cur][ra * 32 + (((2 * khalf) ^ (ra & 7)) * 4)]);
            f32x4 hi = *reinterpret_cast<const f32x4*>(
                &As[cur][ra * 32 + (((2 * khalf + 1) ^ (ra & 7)) * 4)]);
            short h[8] = {f2bf(lo[0]), f2bf(lo[1]), f2bf(lo[2]), f2bf(lo[3]),
                          f2bf(hi[0]), f2bf(hi[1]), f2bf(hi[2]), f2bf(hi[3])};
            av[mf] = *reinterpret_cast<const short8*>(h);
        }
        #pragma unroll
        for (int nf = 0; nf < 4; ++nf) {
            int rb = wc * 64 + nf * 16 + c0;
            bv[nf] = *reinterpret_cast<const short8*>(
                &Bs[cur][rb * 32 + ((khalf ^ ((rb >> 1) & 3)) * 8)]);
        }

        __builtin_amdgcn_s_setprio(1);
        #pragma unroll
        for (int nf = 0; nf < 4; ++nf)
            #pragma unroll
            for (int mf = 0; mf < 4; ++mf)
                acc[mf][nf] = __builtin_amdgcn_mfma_f32_16x16x32_bf16(av[mf], bv[nf], acc[mf][nf], 0, 0, 0);
        __builtin_amdgcn_s_setprio(0);

        asm volatile("s_waitcnt lgkmcnt(0)" ::: "memory");
        __builtin_amdgcn_sched_barrier(0);
        __builtin_amdgcn_s_barrier();      // buf[cur] free for t+2 staging
    }

    // epilogue: per-row partial dot of tanh(h)*W2 over this wave's 64 cols
    float b1v[4], w2v[4];
    #pragma unroll
    for (int nf = 0; nf < 4; ++nf) {
        int gc = col0 + wc * 64 + nf * 16 + c0;
        b1v[nf] = b1[gc];
        w2v[nf] = w2[gc];
    }
    #pragma unroll
    for (int mf = 0; mf < 4; ++mf) {
        #pragma unroll
        for (int reg = 0; reg < 4; ++reg) {
            float s = 0.f;
            #pragma unroll
            for (int nf = 0; nf < 4; ++nf)
                s += fast_tanh(acc[mf][nf][reg] + b1v[nf]) * w2v[nf];
            s += __shfl_xor(s, 1); s += __shfl_xor(s, 2);
            s += __shfl_xor(s, 4); s += __shfl_xor(s, 8);
            if (c0 == 0) gp[wc][wr * 64 + mf * 16 + khalf * 4 + reg] = s;
        }
    }
    __syncthreads();
    if (tid < 128)
        partial[(size_t)(logical & 3) * 32768 + row0 + tid] = gp[0][tid] + gp[1][tid];
}

// ---------------------------------------------------------------------------
// Single-pass per-(b,block): sums the 4 gate partials for member tokens
// (writing gate[] once per valid token), online-softmax stats, ordered lists.
// ---------------------------------------------------------------------------
__global__ void k_blocks(const int* __restrict__ block_ids, const unsigned char* __restrict__ pad,
                         const float* __restrict__ part, const float* __restrict__ b2,
                         float* __restrict__ gate, const int* __restrict__ ct,
                         const float* __restrict__ ct_emb,
                         int* __restrict__ counts, float* __restrict__ mblk,
                         float* __restrict__ wscale, int* __restrict__ lists,
                         float* __restrict__ out_hasb)
{
    const int blk = blockIdx.x;
    const int b = blk >> 7, k = blk & 127;
    const int lane = threadIdx.x;
    const int base = b * NTOK;
    const int lbase = blk * CAP;
    const unsigned long long ltmask = (1ull << lane) - 1ull;
    const float b2v = b2[0];

    float m = -__builtin_inff();
    float s = 0.f;
    int pos = 0;
    for (int t0 = 0; t0 < NTOK; t0 += 64) {
        int t = t0 + lane;
        bool mt = (block_ids[base + t] == k) && (pad[base + t] == 0);
        unsigned long long mask = __ballot(mt);
        if (mt) {
            int r = base + t;
            float g = part[r] + part[32768 + r] + part[65536 + r] + part[98304 + r] + b2v;
            gate[r] = g;   // each valid token belongs to exactly one block -> written once
            int my = pos + __popcll(mask & ltmask);
            if (my < CAP) lists[lbase + my] = t;
            float mn = fmaxf(m, g);
            s = s * __expf(m - mn) + __expf(g - mn);
            m = mn;
        }
        pos += __popcll(mask);
    }
    #pragma unroll
    for (int off = 1; off < 64; off <<= 1) {
        float om = __shfl_xor(m, off);
        float os = __shfl_xor(s, off);
        float mn = fmaxf(m, om);
        float sa = (m == -__builtin_inff()) ? 0.f : s * __expf(m - mn);
        float sb = (om == -__builtin_inff()) ? 0.f : os * __expf(om - mn);
        s = sa + sb;
        m = mn;
    }
    if (lane == 0) {
        counts[blk] = pos;
        mblk[blk] = (pos > 0) ? m : 0.f;
        float mod = 1.0f + 0.1f * ct_emb[ct[b] * NBLK + k];
        wscale[blk] = (pos > 0 && s > 0.f) ? (mod / fmaxf(s, 1e-30f)) : 0.f;
        out_hasb[blk] = (pos > 0) ? 1.f : 0.f;
    }
}

// ---------------------------------------------------------------------------
// Pooling: pooled[b,k,:] = wscale * sum_n exp(gate[n]-m) * x[b,n,:]  (f32 x)
// ---------------------------------------------------------------------------
__global__ void k_pool(const float* __restrict__ x, const float* __restrict__ gate,
                       const int* __restrict__ lists, const int* __restrict__ counts,
                       const float* __restrict__ mblk, const float* __restrict__ wscale,
                       bf16s* __restrict__ pooled)
{
    const int blk = blockIdx.x;
    const int b = blk >> 7;
    const int tid = threadIdx.x;
    const int base = b * NTOK;
    const int cnt = min(counts[blk], CAP);
    const int lbase = blk * CAP;
    const float m = mblk[blk], ws = wscale[blk];

    float4 acc = {0.f, 0.f, 0.f, 0.f};
    for (int i = 0; i < cnt; ++i) {
        int n = lists[lbase + i];
        float w = __expf(gate[base + n] - m);
        float4 xv = *reinterpret_cast<const float4*>(&x[(size_t)(base + n) * HDIM + tid * 4]);
        acc.x += w * xv.x; acc.y += w * xv.y; acc.z += w * xv.z; acc.w += w * xv.w;
    }
    short o[4] = {f2bf(acc.x * ws), f2bf(acc.y * ws), f2bf(acc.z * ws), f2bf(acc.w * ws)};
    *reinterpret_cast<int2*>(&pooled[(size_t)blk * HDIM + tid * 4]) =
        *reinterpret_cast<const int2*>(o);
}

// ---------------------------------------------------------------------------
// GEMM2: y = pooled @ Wp + bp. 1024^3. 64x64 tiles, 4 waves, dbuf + gll,
// counted-vmcnt schedule (vmcnt(2) in-loop, raw barriers).
// ---------------------------------------------------------------------------
__global__ __launch_bounds__(256) void k_gemm2(
    const bf16s* __restrict__ pooled, const bf16s* __restrict__ wpt,
    const float* __restrict__ bp, float* __restrict__ y)
{
    __shared__ alignas(16) bf16s As[2][64 * 32];
    __shared__ alignas(16) bf16s Bs[2][64 * 32];
    const int tid = threadIdx.x;
    const int lane = tid & 63;
    const int wv = tid >> 6;
    const int wr = wv >> 1, wc = wv & 1;
    const int row0 = (blockIdx.x >> 4) * 64, col0 = (blockIdx.x & 15) * 64;
    const int c0 = lane & 15, khalf = lane >> 4;

    const int sr = wv * 16 + (lane >> 2);
    const int sj = (lane & 3) ^ ((sr >> 1) & 3);
    const int sdst = (wv * 16) * 32 + lane * 8;
    const bf16s* srcA = &pooled[(size_t)(row0 + sr) * 1024 + sj * 8];
    const bf16s* srcB = &wpt[(size_t)(col0 + sr) * 1024 + sj * 8];

    f32x4 acc[2][2] = {};

    gload_lds16(srcA, &As[0][sdst]);
    gload_lds16(srcB, &Bs[0][sdst]);

    for (int t = 0; t < 32; ++t) {
        const int cur = t & 1;
        if (t < 31) {
            gload_lds16(srcA + (t + 1) * 32, &As[cur ^ 1][sdst]);
            gload_lds16(srcB + (t + 1) * 32, &Bs[cur ^ 1][sdst]);
            asm volatile("s_waitcnt vmcnt(2)" ::: "memory");
        } else {
            asm volatile("s_waitcnt vmcnt(0)" ::: "memory");
        }
        __builtin_amdgcn_s_barrier();
        __builtin_amdgcn_sched_barrier(0);
        #pragma unroll
        for (int mf = 0; mf < 2; ++mf) {
            int ra = wr * 32 + mf * 16 + c0;
            short8 av = *reinterpret_cast<const short8*>(
                &As[cur][ra * 32 + ((khalf ^ ((ra >> 1) & 3)) * 8)]);
            #pragma unroll
            for (int nf = 0; nf < 2; ++nf) {
                int rb = wc * 32 + nf * 16 + c0;
                short8 bv = *reinterpret_cast<const short8*>(
                    &Bs[cur][rb * 32 + ((khalf ^ ((rb >> 1) & 3)) * 8)]);
                acc[mf][nf] = __builtin_amdgcn_mfma_f32_16x16x32_bf16(av, bv, acc[mf][nf], 0, 0, 0);
            }
        }
        asm volatile("s_waitcnt lgkmcnt(0)" ::: "memory");
        __builtin_amdgcn_sched_barrier(0);
        __builtin_amdgcn_s_barrier();
    }
    #pragma unroll
    for (int mf = 0; mf < 2; ++mf)
        #pragma unroll
        for (int nf = 0; nf < 2; ++nf)
            #pragma unroll
            for (int reg = 0; reg < 4; ++reg) {
                int grow = row0 + wr * 32 + mf * 16 + khalf * 4 + reg;
                int gcol = col0 + wc * 32 + nf * 16 + c0;
                y[(size_t)grow * 1024 + gcol] = acc[mf][nf][reg] + bp[gcol];
            }
}

// ---------------------------------------------------------------------------
// LayerNorm + ELU + present-mask.
// ---------------------------------------------------------------------------
__global__ void k_lnelu(const float* __restrict__ y, const float* __restrict__ ln_g,
                        const float* __restrict__ ln_b, const int* __restrict__ counts,
                        float* __restrict__ outp)
{
    const int row = blockIdx.x;
    const int k = row & 127;
    const int tid = threadIdx.x;

    float4 v = *reinterpret_cast<const float4*>(&y[(size_t)row * 1024 + tid * 4]);
    float s = v.x + v.y + v.z + v.w;
    float ss = v.x * v.x + v.y * v.y + v.z * v.z + v.w * v.w;
    #pragma unroll
    for (int off = 32; off; off >>= 1) { s += __shfl_xor(s, off); ss += __shfl_xor(ss, off); }

    __shared__ float sbuf[4], ssbuf[4];
    int wv = tid >> 6;
    if ((tid & 63) == 0) { sbuf[wv] = s; ssbuf[wv] = ss; }
    __syncthreads();
    s = sbuf[0] + sbuf[1] + sbuf[2] + sbuf[3];
    ss = ssbuf[0] + ssbuf[1] + ssbuf[2] + ssbuf[3];

    float mu = s * (1.f / 1024.f);
    float var = ss * (1.f / 1024.f) - mu * mu;
    float rstd = rsqrtf(var + 1e-5f);

    bool pres = false;
    #pragma unroll
    for (int bb = 0; bb < 8; ++bb) pres = pres || (counts[bb * NBLK + k] > 0);

    float4 g4 = *reinterpret_cast<const float4*>(&ln_g[tid * 4]);
    float4 b4 = *reinterpret_cast<const float4*>(&ln_b[tid * 4]);
    float vals[4] = {v.x, v.y, v.z, v.w};
    float gs[4] = {g4.x, g4.y, g4.z, g4.w};
    float bs[4] = {b4.x, b4.y, b4.z, b4.w};
    float4 o;
    float* op = &o.x;
    #pragma unroll
    for (int j = 0; j < 4; ++j) {
        float t = (vals[j] - mu) * rstd * gs[j] + bs[j];
        t = (t > 0.f) ? t : expm1f(t);
        op[j] = pres ? t : 0.f;
    }
    *reinterpret_cast<float4*>(&outp[(size_t)row * 1024 + tid * 4]) = o;
}

// ---------------------------------------------------------------------------
extern "C" void kernel_launch(void* const* d_in, const int* in_sizes, int n_in,
                              void* d_out, int out_size, void* d_ws, size_t ws_size,
                              hipStream_t stream)
{
    const float* x      = (const float*)d_in[0];
    const int*   ct     = (const int*)d_in[1];
    const int*   bids   = (const int*)d_in[2];
    const unsigned char* pad = (const unsigned char*)d_in[3];
    const float* W1     = (const float*)d_in[4];
    const float* b1     = (const float*)d_in[5];
    const float* W2     = (const float*)d_in[6];
    const float* b2     = (const float*)d_in[7];
    const float* ct_emb = (const float*)d_in[8];
    const float* Wp     = (const float*)d_in[9];
    const float* bp     = (const float*)d_in[10];
    const float* ln_g   = (const float*)d_in[11];
    const float* ln_b   = (const float*)d_in[12];
    float* outF = (float*)d_out;

    char* ws = (char*)d_ws;
    bf16s* w1t    = (bf16s*)(ws + 0);          //  1,048,576
    bf16s* wpt    = (bf16s*)(ws + 1048576);    //  2,097,152 -> 3,145,728
    float* gate   = (float*)(ws + 3145728);    //    131,072 -> 3,276,800
    float* part   = (float*)(ws + 3276800);    //    524,288 -> 3,801,088
    float* mblk   = (float*)(ws + 3801088);
    float* wscal  = (float*)(ws + 3805184);
    int*   counts = (int*)  (ws + 3809280);
    int*   lists  = (int*)  (ws + 3813376);    //  1,048,576 -> 4,861,952
    bf16s* pooled = (bf16s*)(ws + 4861952);    //  2,097,152 -> 6,959,104
    float* ybuf   = (float*)(ws + 6959104);    //  4,194,304 -> 11,153,408

    k_tcvt2<<<dim3(16, 24), 256, 0, stream>>>(W1, Wp, w1t, wpt);
    k_gemm_gf<<<1024, 256, 0, stream>>>(x, w1t, b1, W2, part);
    k_blocks<<<1024, 64, 0, stream>>>(bids, pad, part, b2, gate, ct, ct_emb,
                                      counts, mblk, wscal, lists,
                                      outF + (size_t)8 * NBLK * HDIM);
    k_pool<<<1024, 256, 0, stream>>>(x, gate, lists, counts, mblk, wscal, pooled);
    k_gemm2<<<256, 256, 0, stream>>>(pooled, wpt, bp, ybuf);
    k_lnelu<<<1024, 256, 0, stream>>>(ybuf, ln_g, ln_b, counts, outF);
}